// Round 1
// baseline (94.755 us; speedup 1.0000x reference)
//
#include <hip/hip_runtime.h>
#include <cstdint>
#include <cstddef>

// Problem constants (fixed shapes from setup_inputs)
#define NIMG 4096
#define DFEAT 784      // 4 ch * 14 * 14
#define KPAD 800       // pad to 25 * 32 for MFMA K-steps
#define BM 128
#define BN 128
#define BK 32

typedef __attribute__((ext_vector_type(8))) short  bf16x8;
typedef __attribute__((ext_vector_type(4))) float  f32x4;

__device__ __forceinline__ unsigned short f2bf(float f) {
    unsigned u = __builtin_bit_cast(unsigned, f);
    unsigned r = (u + 0x7fffu + ((u >> 16) & 1u)) >> 16;
    return (unsigned short)r;
}

__device__ __forceinline__ void gload_lds16(const void* g, void* lds) {
    __builtin_amdgcn_global_load_lds(
        (const __attribute__((address_space(1))) unsigned int*)g,
        (__attribute__((address_space(3))) unsigned int*)lds,
        16, 0, 0);
}

// ---------------- feature kernel: conv 2x2 s2 (1->4ch) + bias ----------------
// One block (256 thr) per image. Writes bf16 features [KPAD] (zero-padded
// 784..799) and f32 sum-of-squares norm.
__global__ __launch_bounds__(256)
void feat_kernel(const float* __restrict__ img,       // [NIMG,784] pixels
                 const float* __restrict__ w,         // [4][1][2][2] flat
                 const float* __restrict__ b,         // [4]
                 unsigned short* __restrict__ feat,   // [NIMG][KPAD] bf16 bits
                 float* __restrict__ norms)           // [NIMG]
{
    __shared__ float simg[784];
    __shared__ float partial[4];
    const int n = blockIdx.x;
    const int t = threadIdx.x;
    const float* ip = img + (size_t)n * 784;
    for (int i = t; i < 784; i += 256) simg[i] = ip[i];
    float wr[16];
#pragma unroll
    for (int i = 0; i < 16; ++i) wr[i] = w[i];
    const float br[4] = {b[0], b[1], b[2], b[3]};
    __syncthreads();

    float ss = 0.f;
    unsigned short* op = feat + (size_t)n * KPAD;
    for (int d = t; d < KPAD; d += 256) {
        float f = 0.f;
        if (d < DFEAT) {
            const int c = d / 196;
            const int r = d % 196;
            const int p = r / 14, q = r % 14;
            const float* px = &simg[(2 * p) * 28 + 2 * q];
            f = wr[c * 4 + 0] * px[0] + wr[c * 4 + 1] * px[1]
              + wr[c * 4 + 2] * px[28] + wr[c * 4 + 3] * px[29] + br[c];
            ss += f * f;
        }
        op[d] = f2bf(f);
    }
    // block reduce ss (4 waves)
#pragma unroll
    for (int off = 32; off > 0; off >>= 1) ss += __shfl_down(ss, off, 64);
    if ((t & 63) == 0) partial[t >> 6] = ss;
    __syncthreads();
    if (t == 0) norms[n] = partial[0] + partial[1] + partial[2] + partial[3];
}

// ---------------- Gram kernel: exp(-||fx_i - fy_j||^2) ----------------
// NT GEMM: A=[M][K] fx, B=[N][K] fy, C = A·B^T, 128x128 tile, BK=32,
// 4 waves in 2x2, each wave 64x64 (4x4 fragments of 16x16x32 MFMA).
__global__ __launch_bounds__(256)
void gram_kernel(const unsigned short* __restrict__ A,  // fx bf16 [NIMG][KPAD]
                 const unsigned short* __restrict__ B,  // fy bf16 [NIMG][KPAD]
                 const float* __restrict__ x2,          // [NIMG]
                 const float* __restrict__ y2,          // [NIMG]
                 float* __restrict__ out)               // [NIMG][NIMG]
{
    __shared__ __align__(16) unsigned short As[BM * BK];  // 8 KB
    __shared__ __align__(16) unsigned short Bs[BN * BK];  // 8 KB

    const int t    = threadIdx.x;
    const int lane = t & 63;
    const int w    = t >> 6;          // wave 0..3
    const int wr   = w >> 1;          // wave row 0..1
    const int wc   = w & 1;           // wave col 0..1
    const int bRow = blockIdx.x * BM;
    const int bCol = blockIdx.y * BN;

    f32x4 acc[4][4] = {};

    // staging map: wave w covers 16 rows per call; lane l -> row w*16 + l/4,
    // k-chunk 8*(l%4). LDS dest is wave-uniform base + lane*16 (linear).
    const int srow = (w << 4) + (lane >> 2);
    const int skc  = (lane & 3) << 3;

    const unsigned short* Abase = A + (size_t)(bRow + srow) * KPAD + skc;
    const unsigned short* Bbase = B + (size_t)(bCol + srow) * KPAD + skc;

    const int kq   = (lane >> 4) << 3;   // fragment k offset (0/8/16/24)
    const int frow = lane & 15;          // fragment row/col within 16

    for (int kt = 0; kt < KPAD; kt += BK) {
        // stage A tile (2 rounds of 4 waves x 1KB) + B tile
        gload_lds16(Abase + kt,                    As + w * 512);
        gload_lds16(Abase + (size_t)64 * KPAD + kt, As + 2048 + w * 512);
        gload_lds16(Bbase + kt,                    Bs + w * 512);
        gload_lds16(Bbase + (size_t)64 * KPAD + kt, Bs + 2048 + w * 512);
        __syncthreads();

        bf16x8 af[4], bf[4];
#pragma unroll
        for (int m = 0; m < 4; ++m)
            af[m] = *(const bf16x8*)(As + (wr * 64 + m * 16 + frow) * BK + kq);
#pragma unroll
        for (int n = 0; n < 4; ++n)
            bf[n] = *(const bf16x8*)(Bs + (wc * 64 + n * 16 + frow) * BK + kq);

#pragma unroll
        for (int m = 0; m < 4; ++m)
#pragma unroll
            for (int n = 0; n < 4; ++n)
                acc[m][n] = __builtin_amdgcn_mfma_f32_16x16x32_bf16(
                    af[m], bf[n], acc[m][n], 0, 0, 0);
        __syncthreads();
    }

    // epilogue: C/D layout col=lane&15, row=(lane>>4)*4+j  [m89-verified]
    const int col0 = bCol + wc * 64 + (lane & 15);
    const int row0 = bRow + wr * 64 + ((lane >> 4) << 2);
#pragma unroll
    for (int m = 0; m < 4; ++m) {
#pragma unroll
        for (int n = 0; n < 4; ++n) {
            const int cc = col0 + n * 16;
            const float yn = y2[cc];
#pragma unroll
            for (int j = 0; j < 4; ++j) {
                const int rr = row0 + m * 16 + j;
                float sq = x2[rr] + yn - 2.0f * acc[m][n][j];
                sq = fmaxf(sq, 0.0f);
                out[(size_t)rr * NIMG + cc] = __expf(-sq);
            }
        }
    }
}

extern "C" void kernel_launch(void* const* d_in, const int* in_sizes, int n_in,
                              void* d_out, int out_size, void* d_ws, size_t ws_size,
                              hipStream_t stream) {
    const float* x  = (const float*)d_in[0];
    const float* y  = (const float*)d_in[1];
    const float* cw = (const float*)d_in[2];
    const float* cb = (const float*)d_in[3];
    float* out = (float*)d_out;

    char* ws = (char*)d_ws;
    const size_t featBytes = (size_t)NIMG * KPAD * sizeof(unsigned short); // 6.4 MB
    unsigned short* fx = (unsigned short*)ws;
    unsigned short* fy = (unsigned short*)(ws + featBytes);
    float* x2 = (float*)(ws + 2 * featBytes);
    float* y2 = x2 + NIMG;

    feat_kernel<<<NIMG, 256, 0, stream>>>(x, cw, cb, fx, x2);
    feat_kernel<<<NIMG, 256, 0, stream>>>(y, cw, cb, fy, y2);

    dim3 grid(NIMG / BM, NIMG / BN);
    gram_kernel<<<grid, 256, 0, stream>>>(fx, fy, x2, y2, out);
}

// Round 2
// 55.849 us; speedup vs baseline: 1.6966x; 1.6966x over previous
//
#include <hip/hip_runtime.h>
#include <cstdint>
#include <cstddef>

// Problem constants (fixed shapes from setup_inputs)
#define NIMG 4096
#define NPOS 196       // 14*14 output positions
#define KPAD 832       // 13 * 64, features zero-padded 784..831
#define NT   13        // K tiles of BK
#define BM 128
#define BN 128
#define BK 64

typedef __attribute__((ext_vector_type(8))) short          bf16x8;
typedef __attribute__((ext_vector_type(4))) float          f32x4;
typedef __attribute__((ext_vector_type(4))) unsigned short u16x4;

__device__ __forceinline__ unsigned short f2bf(float f) {
    unsigned u = __builtin_bit_cast(unsigned, f);
    return (unsigned short)((u + 0x7fffu + ((u >> 16) & 1u)) >> 16);
}

__device__ __forceinline__ void gload_lds16(const void* g, void* lds) {
    __builtin_amdgcn_global_load_lds(
        (const __attribute__((address_space(1))) unsigned int*)g,
        (__attribute__((address_space(3))) unsigned int*)lds, 16, 0, 0);
}

// ---------------- feature kernel: conv 2x2 s2 (1->4ch) + bias ----------------
// K-index layout: k = pos*4 + ch (any K permutation preserves dot products).
// One block per image; blocks [0,NIMG) do x, [NIMG,2*NIMG) do y.
__global__ __launch_bounds__(256)
void feat_kernel(const float* __restrict__ imgx,
                 const float* __restrict__ imgy,
                 const float* __restrict__ w,   // [4][1][2][2] flat
                 const float* __restrict__ b,   // [4]
                 unsigned short* __restrict__ fx,
                 unsigned short* __restrict__ fy,
                 float* __restrict__ norms)     // [2*NIMG]: x2 then y2
{
    __shared__ float simg[784];
    __shared__ float partial[4];
    const int gb = blockIdx.x;
    const bool isx = gb < NIMG;
    const int n = isx ? gb : gb - NIMG;
    const int t = threadIdx.x;
    const float* img = isx ? imgx : imgy;
    unsigned short* feat = isx ? fx : fy;

    const float4* ip4 = (const float4*)(img + (size_t)n * 784);
    if (t < 196) ((float4*)simg)[t] = ip4[t];
    __syncthreads();

    float ss = 0.f;
    u16x4 v = (u16x4)0;
    if (t < NPOS) {
        const int p = t / 14, q = t % 14;
        const float* px = &simg[p * 56 + q * 2];
        const float a0 = px[0], a1 = px[1], a2 = px[28], a3 = px[29];
#pragma unroll
        for (int c = 0; c < 4; ++c) {
            const float f = w[c * 4 + 0] * a0 + w[c * 4 + 1] * a1
                          + w[c * 4 + 2] * a2 + w[c * 4 + 3] * a3 + b[c];
            ss += f * f;
            v[c] = (short)f2bf(f);
        }
    }
    if (t < KPAD / 4)
        *(u16x4*)(feat + (size_t)n * KPAD + t * 4) = v;  // t>=NPOS writes zeros

#pragma unroll
    for (int off = 32; off > 0; off >>= 1) ss += __shfl_down(ss, off, 64);
    if ((t & 63) == 0) partial[t >> 6] = ss;
    __syncthreads();
    if (t == 0) norms[gb] = partial[0] + partial[1] + partial[2] + partial[3];
}

// ---------------- Gram kernel: exp(-||fx_i - fy_j||^2) ----------------
// NT GEMM 128x128 tile, BK=64, double-buffered LDS, XOR-swizzled layout:
// logical (row, 16B-chunk c) stored at physical chunk c ^ (row&7).
// Staged via linear global_load_lds with pre-swizzled global source (rule #21).
__global__ __launch_bounds__(256)
void gram_kernel(const unsigned short* __restrict__ A,  // fx bf16 [NIMG][KPAD]
                 const unsigned short* __restrict__ B,  // fy bf16 [NIMG][KPAD]
                 const float* __restrict__ x2,          // [NIMG]
                 const float* __restrict__ y2,          // [NIMG]
                 float* __restrict__ out)               // [NIMG][NIMG]
{
    __shared__ __align__(16) unsigned short As[2][BM * BK];  // 32 KB
    __shared__ __align__(16) unsigned short Bs[2][BN * BK];  // 32 KB

    const int t    = threadIdx.x;
    const int lane = t & 63;
    const int w    = t >> 6;          // wave 0..3
    const int wr   = w >> 1;          // wave row 0..1
    const int wc   = w & 1;           // wave col 0..1

    // XCD-aware swizzle: 1024 blocks, 8 XCDs, 1024%8==0 -> bijective
    const int bid  = blockIdx.x;
    const int swz  = (bid & 7) * 128 + (bid >> 3);
    const int bRow = (swz & 31) * BM;
    const int bCol = (swz >> 5) * BN;

    f32x4 acc[4][4] = {};

    // staging map: 16 chunks of 8 rows x 128B; wave w takes chunks w+4r.
    // lane l -> local row l/8, physical 16B-slot l%8; source k pre-swizzled.
    const int lr    = lane >> 3;
    const int skoff = ((lane & 7) ^ lr) << 3;  // source k element offset

    const unsigned short* Ar[4];
    const unsigned short* Br[4];
#pragma unroll
    for (int r = 0; r < 4; ++r) {
        const int chunk = w + 4 * r;
        Ar[r] = A + (size_t)(bRow + chunk * 8 + lr) * KPAD + skoff;
        Br[r] = B + (size_t)(bCol + chunk * 8 + lr) * KPAD + skoff;
    }

    const int frow = lane & 15;  // fragment row within 16
    const int cq   = lane >> 4;  // fragment k-chunk (elements cq*8)

    // prologue: stage tile 0 into buf 0
#pragma unroll
    for (int r = 0; r < 4; ++r) {
        const int chunk = w + 4 * r;
        gload_lds16(Ar[r], &As[0][chunk * 512]);
        gload_lds16(Br[r], &Bs[0][chunk * 512]);
    }
    __syncthreads();

    int cur = 0;
    for (int kt = 0; kt < NT; ++kt) {
        if (kt + 1 < NT) {
            const int ko = (kt + 1) * BK;
#pragma unroll
            for (int r = 0; r < 4; ++r) {
                const int chunk = w + 4 * r;
                gload_lds16(Ar[r] + ko, &As[cur ^ 1][chunk * 512]);
                gload_lds16(Br[r] + ko, &Bs[cur ^ 1][chunk * 512]);
            }
        }
        const unsigned short* as = As[cur];
        const unsigned short* bs = Bs[cur];
#pragma unroll
        for (int ks = 0; ks < 2; ++ks) {
            const int cb = ks * 4 + cq;   // logical 16B chunk in [0,8)
            bf16x8 af[4], bfr[4];
#pragma unroll
            for (int m = 0; m < 4; ++m) {
                const int row = wr * 64 + m * 16 + frow;
                af[m] = *(const bf16x8*)(as + row * 64 + ((cb ^ (row & 7)) << 3));
            }
#pragma unroll
            for (int n = 0; n < 4; ++n) {
                const int row = wc * 64 + n * 16 + frow;
                bfr[n] = *(const bf16x8*)(bs + row * 64 + ((cb ^ (row & 7)) << 3));
            }
#pragma unroll
            for (int m = 0; m < 4; ++m)
#pragma unroll
                for (int n = 0; n < 4; ++n)
                    acc[m][n] = __builtin_amdgcn_mfma_f32_16x16x32_bf16(
                        af[m], bfr[n], acc[m][n], 0, 0, 0);
        }
        __syncthreads();
        cur ^= 1;
    }

    // epilogue: C/D layout col=lane&15, row=(lane>>4)*4+j  [m89-verified]
    const int col0 = bCol + wc * 64 + frow;
    const int row0 = bRow + wr * 64 + (cq << 2);
#pragma unroll
    for (int m = 0; m < 4; ++m) {
#pragma unroll
        for (int n = 0; n < 4; ++n) {
            const int cc = col0 + n * 16;
            const float yn = y2[cc];
#pragma unroll
            for (int j = 0; j < 4; ++j) {
                const int rr = row0 + m * 16 + j;
                float sq = x2[rr] + yn - 2.0f * acc[m][n][j];
                sq = fmaxf(sq, 0.0f);
                out[(size_t)rr * NIMG + cc] = __expf(-sq);
            }
        }
    }
}

extern "C" void kernel_launch(void* const* d_in, const int* in_sizes, int n_in,
                              void* d_out, int out_size, void* d_ws, size_t ws_size,
                              hipStream_t stream) {
    const float* x  = (const float*)d_in[0];
    const float* y  = (const float*)d_in[1];
    const float* cw = (const float*)d_in[2];
    const float* cb = (const float*)d_in[3];
    float* out = (float*)d_out;

    char* ws = (char*)d_ws;
    const size_t featBytes = (size_t)NIMG * KPAD * sizeof(unsigned short); // 6.8 MB
    unsigned short* fx = (unsigned short*)ws;
    unsigned short* fy = (unsigned short*)(ws + featBytes);
    float* x2 = (float*)(ws + 2 * featBytes);
    float* y2 = x2 + NIMG;

    feat_kernel<<<2 * NIMG, 256, 0, stream>>>(x, y, cw, cb, fx, fy, x2);

    gram_kernel<<<1024, 256, 0, stream>>>(fx, fy, x2, y2, out);
}

// Round 3
// 52.547 us; speedup vs baseline: 1.8032x; 1.0628x over previous
//
#include <hip/hip_runtime.h>
#include <cstdint>
#include <cstddef>

// Problem constants (fixed shapes from setup_inputs)
#define NIMG 4096
#define NPOS 196       // 14*14 output positions
#define KPAD 832       // 13 * 64, features zero-padded 784..831
#define NKT  13        // K tiles of BK=64
#define BM 256
#define BN 256
#define BK 64

typedef __attribute__((ext_vector_type(8))) short          bf16x8;
typedef __attribute__((ext_vector_type(4))) float          f32x4;
typedef __attribute__((ext_vector_type(4))) unsigned short u16x4;

__device__ __forceinline__ unsigned short f2bf(float f) {
    unsigned u = __builtin_bit_cast(unsigned, f);
    return (unsigned short)((u + 0x7fffu + ((u >> 16) & 1u)) >> 16);
}

__device__ __forceinline__ void gload_lds16(const void* g, void* lds) {
    __builtin_amdgcn_global_load_lds(
        (const __attribute__((address_space(1))) unsigned int*)g,
        (__attribute__((address_space(3))) unsigned int*)lds, 16, 0, 0);
}

// ---------------- feature kernel: conv 2x2 s2 (1->4ch) + bias ----------------
// K-index layout: k = pos*4 + ch (K permutation preserves dot products).
__global__ __launch_bounds__(256)
void feat_kernel(const float* __restrict__ imgx,
                 const float* __restrict__ imgy,
                 const float* __restrict__ w,   // [4][1][2][2] flat
                 const float* __restrict__ b,   // [4]
                 unsigned short* __restrict__ fx,
                 unsigned short* __restrict__ fy,
                 float* __restrict__ norms)     // [2*NIMG]: x2 then y2
{
    __shared__ float simg[784];
    __shared__ float partial[4];
    const int gb = blockIdx.x;
    const bool isx = gb < NIMG;
    const int n = isx ? gb : gb - NIMG;
    const int t = threadIdx.x;
    const float* img = isx ? imgx : imgy;
    unsigned short* feat = isx ? fx : fy;

    const float4* ip4 = (const float4*)(img + (size_t)n * 784);
    if (t < 196) ((float4*)simg)[t] = ip4[t];
    __syncthreads();

    float ss = 0.f;
    u16x4 v = (u16x4)0;
    if (t < NPOS) {
        const int p = t / 14, q = t % 14;
        const float* px = &simg[p * 56 + q * 2];
        const float a0 = px[0], a1 = px[1], a2 = px[28], a3 = px[29];
#pragma unroll
        for (int c = 0; c < 4; ++c) {
            const float f = w[c * 4 + 0] * a0 + w[c * 4 + 1] * a1
                          + w[c * 4 + 2] * a2 + w[c * 4 + 3] * a3 + b[c];
            ss += f * f;
            v[c] = (short)f2bf(f);
        }
    }
    if (t < KPAD / 4)
        *(u16x4*)(feat + (size_t)n * KPAD + t * 4) = v;  // t>=NPOS writes zeros

#pragma unroll
    for (int off = 32; off > 0; off >>= 1) ss += __shfl_down(ss, off, 64);
    if ((t & 63) == 0) partial[t >> 6] = ss;
    __syncthreads();
    if (t == 0) norms[gb] = partial[0] + partial[1] + partial[2] + partial[3];
}

// ---------------- Gram kernel: 256x256 tile, 8-phase schedule ----------------
// NT GEMM C = A·B^T with exp(-max(x2+y2-2C,0)) epilogue.
// 8 waves (2M x 4N), BK=64, double-buffered LDS (128 KB), XOR-swizzled layout
// (logical 16B-chunk c of row r stored at c ^ (r&7); pre-swizzled global src).
// Counted vmcnt(4) at phases 4/8 only — prefetch stays in flight across
// barriers (T3+T4); setprio around MFMA clusters (T5).

#define STAGE(GS, LD) do { \
    gload_lds16((GS), (LD)); \
    gload_lds16((GS) + 64 * KPAD, (LD) + 4096); } while (0)

#define DSREADS(BUF, MH, NH) do { \
    _Pragma("unroll") for (int mm = 0; mm < 4; ++mm) { \
        const int row = (MH) * 128 + mm * 32 + wrf; \
        af[mm][0] = *(const bf16x8*)(&As[BUF][0] + (row << 6) + px0); \
        af[mm][1] = *(const bf16x8*)(&As[BUF][0] + (row << 6) + px1); } \
    _Pragma("unroll") for (int nn = 0; nn < 2; ++nn) { \
        const int row = (NH) * 128 + nn * 64 + wcf; \
        bfr[nn][0] = *(const bf16x8*)(&Bs[BUF][0] + (row << 6) + px0); \
        bfr[nn][1] = *(const bf16x8*)(&Bs[BUF][0] + (row << 6) + px1); } \
    } while (0)

#define MFMAS(MH, NH) do { \
    __builtin_amdgcn_s_setprio(1); \
    _Pragma("unroll") for (int mm = 0; mm < 4; ++mm) \
    _Pragma("unroll") for (int nn = 0; nn < 2; ++nn) { \
        acc[(MH)*4+mm][(NH)*2+nn] = __builtin_amdgcn_mfma_f32_16x16x32_bf16( \
            af[mm][0], bfr[nn][0], acc[(MH)*4+mm][(NH)*2+nn], 0, 0, 0); \
        acc[(MH)*4+mm][(NH)*2+nn] = __builtin_amdgcn_mfma_f32_16x16x32_bf16( \
            af[mm][1], bfr[nn][1], acc[(MH)*4+mm][(NH)*2+nn], 0, 0, 0); } \
    __builtin_amdgcn_s_setprio(0); } while (0)

#define BAR() __builtin_amdgcn_s_barrier()
#define LGKM0() do { asm volatile("s_waitcnt lgkmcnt(0)" ::: "memory"); \
                     __builtin_amdgcn_sched_barrier(0); } while (0)
#define VMW(N) asm volatile("s_waitcnt vmcnt(" #N ")" ::: "memory")

__global__ __launch_bounds__(512, 2)
void gram_kernel(const unsigned short* __restrict__ A,  // fx bf16 [NIMG][KPAD]
                 const unsigned short* __restrict__ B,  // fy bf16 [NIMG][KPAD]
                 const float* __restrict__ x2,          // [NIMG]
                 const float* __restrict__ y2,          // [NIMG]
                 float* __restrict__ out)               // [NIMG][NIMG]
{
    __shared__ __align__(16) unsigned short As[2][BM * BK];  // 64 KB
    __shared__ __align__(16) unsigned short Bs[2][BN * BK];  // 64 KB

    const int t    = threadIdx.x;
    const int lane = t & 63;
    const int w    = t >> 6;          // wave 0..7
    const int wr   = w >> 2;          // wave row 0..1
    const int wc   = w & 3;           // wave col 0..3

    // XCD-aware 2D-chunk swizzle: 256 blocks, 8 XCDs, bijective
    const int x = blockIdx.x & 7, c = blockIdx.x >> 3;   // c in [0,32)
    const int bm = ((x >> 1) << 2) | (c & 3);            // [0,16)
    const int bn = ((x & 1) << 3) | (c >> 2);            // [0,16)
    const int bRow = bm * BM;
    const int bCol = bn * BN;

    f32x4 acc[8][4] = {};
    bf16x8 af[4][2], bfr[2][2];

    // fragment-read constants: frow = lane&15, cq = lane>>4
    const int frow = lane & 15;
    const int cq   = lane >> 4;
    const int f7   = frow & 7;
    const int wrf  = wr * 16 + frow;
    const int wcf  = wc * 16 + frow;
    const int px0  = ((cq)     ^ f7) << 3;   // ks=0 physical chunk, elements
    const int px1  = ((4 | cq) ^ f7) << 3;   // ks=1

    // staging: wave w, round r covers half-tile rows r*64 + w*8 + (lane>>3),
    // physical 16B-slot lane&7; source k pre-swizzled (rule #21).
    const int lr    = lane >> 3;
    const int skoff = ((lane & 7) ^ lr) << 3;
    const unsigned short* Asrc = A + (size_t)(bRow + w * 8 + lr) * KPAD + skoff;
    const unsigned short* Bsrc = B + (size_t)(bCol + w * 8 + lr) * KPAD + skoff;

    // LDS dests (wave-uniform): half h at h*8192 elements, wave slot w*512
    unsigned short* lA0h0 = &As[0][(w << 9)];
    unsigned short* lA0h1 = &As[0][8192 + (w << 9)];
    unsigned short* lA1h0 = &As[1][(w << 9)];
    unsigned short* lA1h1 = &As[1][8192 + (w << 9)];
    unsigned short* lB0h0 = &Bs[0][(w << 9)];
    unsigned short* lB0h1 = &Bs[0][8192 + (w << 9)];
    unsigned short* lB1h0 = &Bs[1][(w << 9)];
    unsigned short* lB1h1 = &Bs[1][8192 + (w << 9)];

    // prologue: tile0 full + tile1.A0 + tile1.B1
    STAGE(Asrc,                  lA0h0);
    STAGE(Bsrc,                  lB0h0);
    STAGE(Asrc + 128 * KPAD,     lA0h1);
    STAGE(Bsrc + 128 * KPAD,     lB0h1);
    STAGE(Asrc + 64,             lA1h0);
    STAGE(Bsrc + 128 * KPAD + 64, lB1h1);
    VMW(0);
    BAR();

    // main loop: 6 iterations x 2 K-tiles (tiles 0..11)
    for (int i = 0; i < 6; ++i) {
        const int t1 = (2 * i + 1) * 64, t2 = (2 * i + 2) * 64, t3 = (2 * i + 3) * 64;
        // P1: compute buf0 (m0,n0); stage buf1.A1 <- tile t+1
        DSREADS(0, 0, 0); STAGE(Asrc + 128 * KPAD + t1, lA1h1);
        BAR(); LGKM0(); MFMAS(0, 0); BAR();
        // P2: (m0,n1); stage buf1.B0 <- t+1
        DSREADS(0, 0, 1); STAGE(Bsrc + t1, lB1h0);
        BAR(); LGKM0(); MFMAS(0, 1); BAR();
        // P3: (m1,n1); stage buf0.A0 <- t+2
        DSREADS(0, 1, 1); STAGE(Asrc + t2, lA0h0);
        BAR(); LGKM0(); MFMAS(1, 1); BAR();
        // P4: (m1,n0); stage buf0.B1 <- t+2 ; counted vmcnt
        DSREADS(0, 1, 0); STAGE(Bsrc + 128 * KPAD + t2, lB0h1);
        BAR(); LGKM0(); MFMAS(1, 0); VMW(4); BAR();
        // P5: compute buf1 (m0,n0); stage buf0.A1 <- t+2
        DSREADS(1, 0, 0); STAGE(Asrc + 128 * KPAD + t2, lA0h1);
        BAR(); LGKM0(); MFMAS(0, 0); BAR();
        // P6: (m0,n1); stage buf0.B0 <- t+2
        DSREADS(1, 0, 1); STAGE(Bsrc + t2, lB0h0);
        BAR(); LGKM0(); MFMAS(0, 1); BAR();
        // P7: (m1,n1); stage buf1.A0 <- t+3 (tile exists only for i<5)
        DSREADS(1, 1, 1); if (i < 5) STAGE(Asrc + t3, lA1h0);
        BAR(); LGKM0(); MFMAS(1, 1); BAR();
        // P8: (m1,n0); stage buf1.B1 <- t+3 ; counted vmcnt (drain if last)
        DSREADS(1, 1, 0); if (i < 5) STAGE(Bsrc + 128 * KPAD + t3, lB1h1);
        BAR(); LGKM0(); MFMAS(1, 0);
        if (i < 5) { VMW(4); } else { VMW(0); }
        BAR();
    }

    // tail: tile 12 in buf0, fully staged+drained; no barriers needed
    DSREADS(0, 0, 0); MFMAS(0, 0);
    DSREADS(0, 0, 1); MFMAS(0, 1);
    DSREADS(0, 1, 1); MFMAS(1, 1);
    DSREADS(0, 1, 0); MFMAS(1, 0);
    __builtin_amdgcn_sched_barrier(0);

    // epilogue: C/D layout col=lane&15, row=(lane>>4)*4+j  [m89-verified]
    const int row_base = bRow + wr * 16 + (cq << 2);
    const int col_base = bCol + wc * 16 + frow;
#pragma unroll
    for (int n = 0; n < 4; ++n) {
        const float yn = y2[col_base + n * 64];
#pragma unroll
        for (int m = 0; m < 8; ++m) {
#pragma unroll
            for (int j = 0; j < 4; ++j) {
                const int rr = row_base + m * 32 + j;
                float sq = fmaxf(x2[rr] + yn - 2.0f * acc[m][n][j], 0.0f);
                out[(size_t)rr * NIMG + col_base + n * 64] = __expf(-sq);
            }
        }
    }
}

extern "C" void kernel_launch(void* const* d_in, const int* in_sizes, int n_in,
                              void* d_out, int out_size, void* d_ws, size_t ws_size,
                              hipStream_t stream) {
    const float* x  = (const float*)d_in[0];
    const float* y  = (const float*)d_in[1];
    const float* cw = (const float*)d_in[2];
    const float* cb = (const float*)d_in[3];
    float* out = (float*)d_out;

    char* ws = (char*)d_ws;
    const size_t featBytes = (size_t)NIMG * KPAD * sizeof(unsigned short); // 6.8 MB
    unsigned short* fx = (unsigned short*)ws;
    unsigned short* fy = (unsigned short*)(ws + featBytes);
    float* x2 = (float*)(ws + 2 * featBytes);
    float* y2 = x2 + NIMG;

    feat_kernel<<<2 * NIMG, 256, 0, stream>>>(x, y, cw, cb, fx, fy, x2);

    gram_kernel<<<256, 512, 0, stream>>>(fx, fy, x2, y2, out);
}

// Round 4
// 47.592 us; speedup vs baseline: 1.9910x; 1.1041x over previous
//
#include <hip/hip_runtime.h>
#include <cstdint>
#include <cstddef>

// Problem constants (fixed shapes from setup_inputs)
#define NIMG 4096
#define NPOS 196       // 14*14 output positions
#define KPAD 832       // 13 * 64, features zero-padded 784..831
#define BM 256
#define BN 256
#define BK 64

typedef __attribute__((ext_vector_type(8)))  short          bf16x8;
typedef __attribute__((ext_vector_type(16))) float          f32x16;
typedef __attribute__((ext_vector_type(4)))  float          f32x4;
typedef __attribute__((ext_vector_type(4)))  unsigned short u16x4;

__device__ __forceinline__ unsigned short f2bf(float f) {
    unsigned u = __builtin_bit_cast(unsigned, f);
    return (unsigned short)((u + 0x7fffu + ((u >> 16) & 1u)) >> 16);
}

__device__ __forceinline__ void gload_lds16(const void* g, void* lds) {
    __builtin_amdgcn_global_load_lds(
        (const __attribute__((address_space(1))) unsigned int*)g,
        (__attribute__((address_space(3))) unsigned int*)lds, 16, 0, 0);
}

// ---------------- feature kernel: conv 2x2 s2 (1->4ch) + bias ----------------
// K-index layout: k = pos*4 + ch (K permutation preserves dot products).
__global__ __launch_bounds__(256)
void feat_kernel(const float* __restrict__ imgx,
                 const float* __restrict__ imgy,
                 const float* __restrict__ w,   // [4][1][2][2] flat
                 const float* __restrict__ b,   // [4]
                 unsigned short* __restrict__ fx,
                 unsigned short* __restrict__ fy,
                 float* __restrict__ norms)     // [2*NIMG]: x2 then y2
{
    __shared__ float simg[784];
    __shared__ float partial[4];
    const int gb = blockIdx.x;
    const bool isx = gb < NIMG;
    const int n = isx ? gb : gb - NIMG;
    const int t = threadIdx.x;
    const float* img = isx ? imgx : imgy;
    unsigned short* feat = isx ? fx : fy;

    const float4* ip4 = (const float4*)(img + (size_t)n * 784);
    if (t < 196) ((float4*)simg)[t] = ip4[t];
    __syncthreads();

    float ss = 0.f;
    u16x4 v = (u16x4)0;
    if (t < NPOS) {
        const int p = t / 14, q = t % 14;
        const float* px = &simg[p * 56 + q * 2];
        const float a0 = px[0], a1 = px[1], a2 = px[28], a3 = px[29];
#pragma unroll
        for (int c = 0; c < 4; ++c) {
            const float f = w[c * 4 + 0] * a0 + w[c * 4 + 1] * a1
                          + w[c * 4 + 2] * a2 + w[c * 4 + 3] * a3 + b[c];
            ss += f * f;
            v[c] = (short)f2bf(f);
        }
    }
    if (t < KPAD / 4)
        *(u16x4*)(feat + (size_t)n * KPAD + t * 4) = v;  // t>=NPOS writes zeros

#pragma unroll
    for (int off = 32; off > 0; off >>= 1) ss += __shfl_down(ss, off, 64);
    if ((t & 63) == 0) partial[t >> 6] = ss;
    __syncthreads();
    if (t == 0) norms[gb] = partial[0] + partial[1] + partial[2] + partial[3];
}

// ---------------- Gram kernel: 256x256, 32x32x16 MFMA, 8-phase -------------
// NT GEMM C = A·B^T with exp(-max(x2+y2-2C,0)) epilogue.
// 8 waves (2M x 4N), BK=64, double-buffered LDS (128 KB), XOR-swizzled.
// Fragment reuse: per K-tile phases read {A0+B0, B1, A1, -} = 24 reads
// (minimum operand footprint). Counted vmcnt(4) at phases 4/8 (T4);
// setprio around MFMA (T5). Staging/liveness identical to verified r3.

#define STAGE(GS, LD) do { \
    gload_lds16((GS), (LD)); \
    gload_lds16((GS) + 64 * KPAD, (LD) + 4096); } while (0)

#define RD_A(BUF, MH) do { \
    _Pragma("unroll") for (int mm = 0; mm < 2; ++mm) \
    _Pragma("unroll") for (int ks = 0; ks < 4; ++ks) \
        af[mm][ks] = *(const bf16x8*)(&As[BUF][0] \
            + (((MH) * 128 + mm * 64 + wrow) << 6) + px[ks]); } while (0)

#define RD_B(BUF, NH, BV) do { \
    _Pragma("unroll") for (int ks = 0; ks < 4; ++ks) \
        BV[ks] = *(const bf16x8*)(&Bs[BUF][0] \
            + (((NH) * 128 + wcol) << 6) + px[ks]); } while (0)

#define MFMAS(MH, NH, BV) do { \
    __builtin_amdgcn_s_setprio(1); \
    _Pragma("unroll") for (int ks = 0; ks < 4; ++ks) \
    _Pragma("unroll") for (int mm = 0; mm < 2; ++mm) \
        acc[(MH)*2+mm][NH] = __builtin_amdgcn_mfma_f32_32x32x16_bf16( \
            af[mm][ks], BV[ks], acc[(MH)*2+mm][NH], 0, 0, 0); \
    __builtin_amdgcn_s_setprio(0); } while (0)

// epilogue for quadrant (MH,NH): C/D layout col=lane&31,
// row=(reg&3)+8*(reg>>2)+4*(lane>>5)  [m74/m101-verified]
#define EPI(MH, NH) do { \
    const int colg = bCol + (NH) * 128 + wcol; \
    const float yv = y2[colg]; \
    _Pragma("unroll") for (int mm = 0; mm < 2; ++mm) { \
        const int rbase = bRow + (MH) * 128 + mm * 64 + wr * 32 + 4 * hi; \
        _Pragma("unroll") for (int q = 0; q < 4; ++q) { \
            const f32x4 xv = *(const f32x4*)&x2[rbase + 8 * q]; \
            _Pragma("unroll") for (int j = 0; j < 4; ++j) { \
                float sq = fmaxf(xv[j] + yv \
                    - 2.0f * acc[(MH)*2+mm][NH][q * 4 + j], 0.0f); \
                out[(size_t)(rbase + 8 * q + j) * NIMG + colg] = __expf(-sq); \
            } } } } while (0)

#define BAR() __builtin_amdgcn_s_barrier()
#define LGKM0() do { asm volatile("s_waitcnt lgkmcnt(0)" ::: "memory"); \
                     __builtin_amdgcn_sched_barrier(0); } while (0)
#define VMW(N) asm volatile("s_waitcnt vmcnt(" #N ")" ::: "memory")

__global__ __launch_bounds__(512, 2)
void gram_kernel(const unsigned short* __restrict__ A,  // fx bf16 [NIMG][KPAD]
                 const unsigned short* __restrict__ B,  // fy bf16 [NIMG][KPAD]
                 const float* __restrict__ x2,          // [NIMG]
                 const float* __restrict__ y2,          // [NIMG]
                 float* __restrict__ out)               // [NIMG][NIMG]
{
    __shared__ __align__(16) unsigned short As[2][BM * BK];  // 64 KB
    __shared__ __align__(16) unsigned short Bs[2][BN * BK];  // 64 KB

    const int t    = threadIdx.x;
    const int lane = t & 63;
    const int w    = t >> 6;          // wave 0..7
    const int wr   = w >> 2;          // wave row 0..1
    const int wc   = w & 3;           // wave col 0..3

    // XCD-aware 2D-chunk swizzle: 256 blocks, 8 XCDs, bijective
    const int x = blockIdx.x & 7, c = blockIdx.x >> 3;   // c in [0,32)
    const int bm = ((x >> 1) << 2) | (c & 3);            // [0,16)
    const int bn = ((x & 1) << 3) | (c >> 2);            // [0,16)
    const int bRow = bm * BM;
    const int bCol = bn * BN;

    f32x16 acc[4][2] = {};       // [mh*2+mm][nh], 128 regs
    bf16x8 af[2][4];             // A frags: [mm][ks]
    bf16x8 b0[4], b1[4];         // B frags for NH=0 / NH=1

    // fragment-read constants (32x32x16: row=lane&31, k=(lane>>5)*8+j)
    const int r32  = lane & 31;
    const int hi   = lane >> 5;
    const int f7   = lane & 7;
    const int wrow = wr * 32 + r32;   // A row within half (row&7 == f7)
    const int wcol = wc * 32 + r32;   // B col within half
    int px[4];
#pragma unroll
    for (int ks = 0; ks < 4; ++ks) px[ks] = ((2 * ks + hi) ^ f7) << 3;

    // staging: wave w covers rows w*8 + (lane>>3) of each 64-row group,
    // physical 16B-slot lane&7; source k pre-swizzled (rule #21).
    const int lr    = lane >> 3;
    const int skoff = ((lane & 7) ^ lr) << 3;
    const unsigned short* Asrc = A + (size_t)(bRow + w * 8 + lr) * KPAD + skoff;
    const unsigned short* Bsrc = B + (size_t)(bCol + w * 8 + lr) * KPAD + skoff;

    // LDS dests (wave-uniform): half h at h*8192 elements, wave slot w*512
    unsigned short* lA0h0 = &As[0][(w << 9)];
    unsigned short* lA0h1 = &As[0][8192 + (w << 9)];
    unsigned short* lA1h0 = &As[1][(w << 9)];
    unsigned short* lA1h1 = &As[1][8192 + (w << 9)];
    unsigned short* lB0h0 = &Bs[0][(w << 9)];
    unsigned short* lB0h1 = &Bs[0][8192 + (w << 9)];
    unsigned short* lB1h0 = &Bs[1][(w << 9)];
    unsigned short* lB1h1 = &Bs[1][8192 + (w << 9)];

    // prologue: tile0 full into buf0 + tile1.A0 + tile1.B1
    STAGE(Asrc,                   lA0h0);
    STAGE(Bsrc,                   lB0h0);
    STAGE(Asrc + 128 * KPAD,      lA0h1);
    STAGE(Bsrc + 128 * KPAD,      lB0h1);
    STAGE(Asrc + 64,              lA1h0);
    STAGE(Bsrc + 128 * KPAD + 64, lB1h1);
    VMW(0);
    BAR();

    // main loop: 6 iterations x 2 K-tiles (tiles 0..11)
    for (int i = 0; i < 6; ++i) {
        const int t1 = (2 * i + 1) * 64, t2 = (2 * i + 2) * 64, t3 = (2 * i + 3) * 64;
        // P1: read A0+B0 of buf0; stage buf1.A1 <- t+1
        RD_A(0, 0); RD_B(0, 0, b0); STAGE(Asrc + 128 * KPAD + t1, lA1h1);
        BAR(); LGKM0(); MFMAS(0, 0, b0); BAR();
        // P2: read B1; stage buf1.B0 <- t+1
        RD_B(0, 1, b1); STAGE(Bsrc + t1, lB1h0);
        BAR(); LGKM0(); MFMAS(0, 1, b1); BAR();
        // P3: read A1; stage buf0.A0 <- t+2
        RD_A(0, 1); STAGE(Asrc + t2, lA0h0);
        BAR(); LGKM0(); MFMAS(1, 1, b1); BAR();
        // P4: pure-MFMA (reuses af,b0); stage buf0.B1 <- t+2 ; counted vmcnt
        STAGE(Bsrc + 128 * KPAD + t2, lB0h1);
        MFMAS(1, 0, b0); VMW(4); BAR();
        // P5: read A0+B0 of buf1; stage buf0.A1 <- t+2
        RD_A(1, 0); RD_B(1, 0, b0); STAGE(Asrc + 128 * KPAD + t2, lA0h1);
        BAR(); LGKM0(); MFMAS(0, 0, b0); BAR();
        // P6: read B1; stage buf0.B0 <- t+2
        RD_B(1, 1, b1); STAGE(Bsrc + t2, lB0h0);
        BAR(); LGKM0(); MFMAS(0, 1, b1); BAR();
        // P7: read A1; stage buf1.A0 <- t+3 (exists only for i<5)
        RD_A(1, 1); if (i < 5) STAGE(Asrc + t3, lA1h0);
        BAR(); LGKM0(); MFMAS(1, 1, b1); BAR();
        // P8: pure-MFMA; stage buf1.B1 <- t+3 ; counted vmcnt (drain if last)
        if (i < 5) STAGE(Bsrc + 128 * KPAD + t3, lB1h1);
        MFMAS(1, 0, b0);
        if (i < 5) { VMW(4); } else { VMW(0); }
        BAR();
    }

    // tail: tile 12 in buf0 (fully staged + drained); interleave epilogue
    RD_A(0, 0); RD_B(0, 0, b0); LGKM0();
    MFMAS(0, 0, b0); EPI(0, 0);
    RD_B(0, 1, b1); LGKM0();
    MFMAS(0, 1, b1); EPI(0, 1);
    RD_A(0, 1); LGKM0();
    MFMAS(1, 1, b1); EPI(1, 1);
    MFMAS(1, 0, b0); EPI(1, 0);
}

extern "C" void kernel_launch(void* const* d_in, const int* in_sizes, int n_in,
                              void* d_out, int out_size, void* d_ws, size_t ws_size,
                              hipStream_t stream) {
    const float* x  = (const float*)d_in[0];
    const float* y  = (const float*)d_in[1];
    const float* cw = (const float*)d_in[2];
    const float* cb = (const float*)d_in[3];
    float* out = (float*)d_out;

    char* ws = (char*)d_ws;
    const size_t featBytes = (size_t)NIMG * KPAD * sizeof(unsigned short); // 6.8 MB
    unsigned short* fx = (unsigned short*)ws;
    unsigned short* fy = (unsigned short*)(ws + featBytes);
    float* x2 = (float*)(ws + 2 * featBytes);
    float* y2 = x2 + NIMG;

    feat_kernel<<<2 * NIMG, 256, 0, stream>>>(x, y, cw, cb, fx, fy, x2);

    gram_kernel<<<256, 512, 0, stream>>>(fx, fy, x2, y2, out);
}

// Round 5
// 42.385 us; speedup vs baseline: 2.2356x; 1.1228x over previous
//
#include <hip/hip_runtime.h>
#include <cstdint>
#include <cstddef>

// Problem constants (fixed shapes from setup_inputs)
#define NIMG 4096
#define NPOS 196       // 14*14 output positions
#define KPAD 896       // 7 * 128, fp8 features zero-padded 784..895
#define NKT  7         // K tiles of BK=128
#define BM 256
#define BN 256

typedef __attribute__((ext_vector_type(16))) float f32x16;
typedef __attribute__((ext_vector_type(4)))  float f32x4;
typedef __attribute__((ext_vector_type(4)))  int   i32x4;
typedef __attribute__((ext_vector_type(2)))  long  l64x2;

__device__ __forceinline__ void gload_lds16(const void* g, void* lds) {
    __builtin_amdgcn_global_load_lds(
        (const __attribute__((address_space(1))) unsigned int*)g,
        (__attribute__((address_space(3))) unsigned int*)lds, 16, 0, 0);
}

// ---------------- feature kernel: conv 2x2 s2 (1->4ch) + bias, fp8 ----------
// Logical K layout: k = pos*4 + ch (K permutation preserves dot products).
// Stored layout bakes in (a) hi-interleave per 32-B unit so one b128 LDS read
// = two MFMA K-steps for the lane's hi-half: within unit, logical 8-groups
// [0,8,16,24] -> positions [0,16,8,24] (swap bits 3,4); (b) XOR swizzle of
// 16-B slots within each 128-B K-slice with key n&7 (2-way/free ds_read, and
// staging reads contiguous stored bytes -> linear global_load_lds works).
__global__ __launch_bounds__(256)
void feat_kernel(const float* __restrict__ imgx,
                 const float* __restrict__ imgy,
                 const float* __restrict__ w,   // [4][1][2][2] flat
                 const float* __restrict__ b,   // [4]
                 unsigned char* __restrict__ fx,
                 unsigned char* __restrict__ fy,
                 float* __restrict__ norms)     // [2*NIMG]: x2 then y2
{
    __shared__ float simg[784];
    __shared__ float partial[4];
    const int gb = blockIdx.x;
    const bool isx = gb < NIMG;
    const int n = isx ? gb : gb - NIMG;
    const int t = threadIdx.x;
    const float* img = isx ? imgx : imgy;
    unsigned char* feat = isx ? fx : fy;

    const float4* ip4 = (const float4*)(img + (size_t)n * 784);
    if (t < 196) ((float4*)simg)[t] = ip4[t];
    __syncthreads();

    float ss = 0.f;
    unsigned pack = 0u;
    if (t < NPOS) {
        const int p = t / 14, q = t % 14;
        const float* px = &simg[p * 56 + q * 2];
        const float a0 = px[0], a1 = px[1], a2 = px[28], a3 = px[29];
        float f[4];
#pragma unroll
        for (int c = 0; c < 4; ++c) {
            f[c] = w[c * 4 + 0] * a0 + w[c * 4 + 1] * a1
                 + w[c * 4 + 2] * a2 + w[c * 4 + 3] * a3 + b[c];
            ss += f[c] * f[c];
        }
        pack = __builtin_amdgcn_cvt_pk_fp8_f32(f[0], f[1], 0, false);
        pack = __builtin_amdgcn_cvt_pk_fp8_f32(f[2], f[3], pack, true);
    }
    if (t < KPAD / 4) {
        // position of logical bytes k = 4t..4t+3 in stored layout
        const int u   = t >> 3;             // 32-B unit
        const int w5  = (t & 7) * 4;        // offset within unit
        const int pin = (w5 & 7) | ((w5 & 8) << 1) | ((w5 & 16) >> 1);
        const int p   = (u << 5) | pin;     // after hi-interleave
        const int s3  = (p >> 4) & 7;       // 16-B slot within 128-B slice
        const int pf  = (p & ~127) | (((s3 ^ (n & 7)) << 4) | (p & 15));
        *(unsigned*)(feat + (size_t)n * KPAD + pf) = pack;  // zeros if t>=196
    }

#pragma unroll
    for (int off = 32; off > 0; off >>= 1) ss += __shfl_down(ss, off, 64);
    if ((t & 63) == 0) partial[t >> 6] = ss;
    __syncthreads();
    if (t == 0) norms[gb] = partial[0] + partial[1] + partial[2] + partial[3];
}

// ---------------- Gram kernel: 256x256, fp8 32x32x16 MFMA, BK=128 ----------
// NT GEMM C = A·B^T with exp(-max(x2+y2-2C,0)) epilogue.
// 8 waves (2M x 4N), double-buffered LDS (128 KB), 2 phases per K-tile,
// 4 independent MFMA chains (reuse gap 4), counted vmcnt(2) per K-tile.

#define STAGE(GS, LD) do { \
    gload_lds16((GS), (LD)); \
    gload_lds16((GS) + 64 * KPAD, (LD) + 8192); } while (0)

#define RD_A(BUF, MH) do { \
    _Pragma("unroll") for (int mm = 0; mm < 2; ++mm) \
    _Pragma("unroll") for (int q = 0; q < 4; ++q) \
        af[mm][q] = __builtin_bit_cast(l64x2, *(const i32x4*)(&As[BUF][0] \
            + (((MH) * 128 + mm * 64 + wrow) << 7) + pxq[q])); } while (0)

#define RD_B(BUF, NH, BV) do { \
    _Pragma("unroll") for (int q = 0; q < 4; ++q) \
        BV[q] = __builtin_bit_cast(l64x2, *(const i32x4*)(&Bs[BUF][0] \
            + (((NH) * 128 + wcol) << 7) + pxq[q])); } while (0)

#define MFMA_MH(MH) do { \
    __builtin_amdgcn_s_setprio(1); \
    _Pragma("unroll") for (int q = 0; q < 4; ++q) \
    _Pragma("unroll") for (int h = 0; h < 2; ++h) { \
        const long a0 = af[0][q][h], a1 = af[1][q][h]; \
        const long v0 = b0[q][h],    v1 = b1[q][h]; \
        acc[(MH)*2+0][0] = __builtin_amdgcn_mfma_f32_32x32x16_fp8_fp8( \
            a0, v0, acc[(MH)*2+0][0], 0, 0, 0); \
        acc[(MH)*2+1][0] = __builtin_amdgcn_mfma_f32_32x32x16_fp8_fp8( \
            a1, v0, acc[(MH)*2+1][0], 0, 0, 0); \
        acc[(MH)*2+0][1] = __builtin_amdgcn_mfma_f32_32x32x16_fp8_fp8( \
            a0, v1, acc[(MH)*2+0][1], 0, 0, 0); \
        acc[(MH)*2+1][1] = __builtin_amdgcn_mfma_f32_32x32x16_fp8_fp8( \
            a1, v1, acc[(MH)*2+1][1], 0, 0, 0); \
    } \
    __builtin_amdgcn_s_setprio(0); } while (0)

// epilogue for half MH: C/D layout col=lane&31, row=(reg&3)+8*(reg>>2)+4*hi
#define EPI(MH) do { \
    _Pragma("unroll") for (int nh = 0; nh < 2; ++nh) { \
        const int colg = bCol + nh * 128 + wcol; \
        const float yv = y2[colg]; \
        _Pragma("unroll") for (int mm = 0; mm < 2; ++mm) { \
            const int rbase = bRow + (MH) * 128 + mm * 64 + wr * 32 + 4 * hi; \
            _Pragma("unroll") for (int gq = 0; gq < 4; ++gq) { \
                const f32x4 xv = *(const f32x4*)&x2[rbase + 8 * gq]; \
                _Pragma("unroll") for (int j = 0; j < 4; ++j) { \
                    float sq = fmaxf(xv[j] + yv \
                        - 2.0f * acc[(MH)*2+mm][nh][gq * 4 + j], 0.0f); \
                    out[(size_t)(rbase + 8 * gq + j) * NIMG + colg] = \
                        __expf(-sq); \
                } } } } } while (0)

#define BAR() __builtin_amdgcn_s_barrier()
#define LGKM0() do { asm volatile("s_waitcnt lgkmcnt(0)" ::: "memory"); \
                     __builtin_amdgcn_sched_barrier(0); } while (0)
#define VMW(N) asm volatile("s_waitcnt vmcnt(" #N ")" ::: "memory")

__global__ __launch_bounds__(512, 2)
void gram_kernel(const unsigned char* __restrict__ A,  // fx fp8 [NIMG][KPAD]
                 const unsigned char* __restrict__ B,  // fy fp8 [NIMG][KPAD]
                 const float* __restrict__ x2,         // [NIMG]
                 const float* __restrict__ y2,         // [NIMG]
                 float* __restrict__ out)              // [NIMG][NIMG]
{
    __shared__ __align__(16) unsigned char As[2][BM * 128];  // 64 KB
    __shared__ __align__(16) unsigned char Bs[2][BN * 128];  // 64 KB

    const int t    = threadIdx.x;
    const int lane = t & 63;
    const int w    = t >> 6;          // wave 0..7
    const int wr   = w >> 2;          // wave row 0..1
    const int wc   = w & 3;           // wave col 0..3

    // XCD-aware 2D-chunk swizzle: 256 blocks, 8 XCDs, bijective
    const int xb = blockIdx.x & 7, cb = blockIdx.x >> 3;  // cb in [0,32)
    const int bm = ((xb >> 1) << 2) | (cb & 3);           // [0,16)
    const int bn = ((xb & 1) << 3) | (cb >> 2);           // [0,16)
    const int bRow = bm * BM;
    const int bCol = bn * BN;

    f32x16 acc[4][2] = {};       // [mh*2+mm][nh], 128 regs
    l64x2 af[2][4];              // A frags: [mm][unit]
    l64x2 b0[4], b1[4];          // B frags for NH=0 / NH=1

    // fragment-read constants (32x32 fp8: row/col = lane&31, k=(lane>>5)*8+j)
    const int r32  = lane & 31;
    const int hi   = lane >> 5;
    const int f7   = r32 & 7;
    const int wrow = wr * 32 + r32;   // A row within half
    const int wcol = wc * 32 + r32;   // B col within half
    int pxq[4];
#pragma unroll
    for (int q = 0; q < 4; ++q) pxq[q] = (((q << 1) | hi) ^ f7) << 4;

    // staging: wave w covers rows w*8 + (lane>>3) of each 64-row group,
    // 16-B col chunk lane&7; stored layout is pre-swizzled -> linear copy.
    const int lr = lane >> 3;
    const unsigned char* Asrc = A + (size_t)(bRow + w * 8 + lr) * KPAD
                                  + (lane & 7) * 16;
    const unsigned char* Bsrc = B + (size_t)(bCol + w * 8 + lr) * KPAD
                                  + (lane & 7) * 16;

    // LDS dests (wave-uniform): half h at h*16384, wave slot w*1024
    unsigned char* dA0h0 = &As[0][w << 10];
    unsigned char* dA0h1 = &As[0][16384 + (w << 10)];
    unsigned char* dA1h0 = &As[1][w << 10];
    unsigned char* dA1h1 = &As[1][16384 + (w << 10)];
    unsigned char* dB0h0 = &Bs[0][w << 10];
    unsigned char* dB0h1 = &Bs[0][16384 + (w << 10)];
    unsigned char* dB1h0 = &Bs[1][w << 10];
    unsigned char* dB1h1 = &Bs[1][16384 + (w << 10)];

    // prologue: tile0 full into buf0 + tile1.Ah0 into buf1
    STAGE(Asrc,              dA0h0);
    STAGE(Bsrc,              dB0h0);
    STAGE(Asrc + 128 * KPAD, dA0h1);
    STAGE(Bsrc + 128 * KPAD, dB0h1);
    STAGE(Asrc + 128,        dA1h0);
    VMW(2);
    BAR();

    // main loop: tiles 0..5 (tile t in buf t&1)
    for (int kt = 0; kt < 6; ++kt) {
        const int c   = kt & 1;
        const int o1  = (kt + 1) * 128;   // next tile k-byte offset
        const int o2  = (kt + 2) * 128;
        unsigned char* nAh1 = c ? dA0h1 : dA1h1;
        unsigned char* nBh0 = c ? dB0h0 : dB1h0;
        unsigned char* nBh1 = c ? dB0h1 : dB1h1;
        unsigned char* cAh0 = c ? dA1h0 : dA0h0;
        // Q1: read Ah0 + both B halves; stage next-tile Ah1, Bh0
        RD_A(c, 0); RD_B(c, 0, b0); RD_B(c, 1, b1);
        STAGE(Asrc + 128 * KPAD + o1, nAh1);
        STAGE(Bsrc + o1,              nBh0);
        BAR(); LGKM0(); MFMA_MH(0); BAR();
        // Q2: read Ah1; stage next-tile Bh1 + tile(t+2).Ah0 into cur buf
        RD_A(c, 1);
        STAGE(Bsrc + 128 * KPAD + o1, nBh1);
        if (kt < 5) STAGE(Asrc + o2, cAh0);
        BAR(); LGKM0(); MFMA_MH(1);
        if (kt < 5) { VMW(2); } else { VMW(0); }
        BAR();
    }

    // tail: tile 6 in buf0, fully staged + drained; epilogue interleaved
    RD_A(0, 0); RD_B(0, 0, b0); RD_B(0, 1, b1);
    LGKM0(); MFMA_MH(0); EPI(0);
    RD_A(0, 1);
    LGKM0(); MFMA_MH(1); EPI(1);
}

extern "C" void kernel_launch(void* const* d_in, const int* in_sizes, int n_in,
                              void* d_out, int out_size, void* d_ws, size_t ws_size,
                              hipStream_t stream) {
    const float* x  = (const float*)d_in[0];
    const float* y  = (const float*)d_in[1];
    const float* cw = (const float*)d_in[2];
    const float* cb = (const float*)d_in[3];
    float* out = (float*)d_out;

    char* ws = (char*)d_ws;
    const size_t featBytes = (size_t)NIMG * KPAD;  // 3.67 MB
    unsigned char* fx = (unsigned char*)ws;
    unsigned char* fy = (unsigned char*)(ws + featBytes);
    float* x2 = (float*)(ws + 2 * featBytes);
    float* y2 = x2 + NIMG;

    feat_kernel<<<2 * NIMG, 256, 0, stream>>>(x, y, cw, cb, fx, fy, x2);

    gram_kernel<<<256, 512, 0, stream>>>(fx, fy, x2, y2, out);
}

// Round 6
// 35.411 us; speedup vs baseline: 2.6759x; 1.1970x over previous
//
#include <hip/hip_runtime.h>
#include <cstdint>
#include <cstddef>

// Problem constants (fixed shapes from setup_inputs)
#define NIMG 4096
#define NPOS 196       // 14*14 output positions
#define KPAD 896       // 7 * 128, fp8 features zero-padded 784..895
#define NKT  7         // K tiles of BK=128
#define BM 256
#define BN 256

typedef __attribute__((ext_vector_type(16))) float f32x16;
typedef __attribute__((ext_vector_type(4)))  float f32x4;
typedef __attribute__((ext_vector_type(4)))  int   i32x4;
typedef __attribute__((ext_vector_type(8)))  int   i32x8;

__device__ __forceinline__ void gload_lds16(const void* g, void* lds) {
    __builtin_amdgcn_global_load_lds(
        (const __attribute__((address_space(1))) unsigned int*)g,
        (__attribute__((address_space(3))) unsigned int*)lds, 16, 0, 0);
}

// ---------------- feature kernel: conv 2x2 s2 (1->4ch) + bias, fp8 ----------
// Logical K layout: k = pos*4 + ch (K permutation preserves dot products).
// Stored layout: plain linear k within each 128-B K-slice, with XOR swizzle
// of 16-B slots keyed by n&7 (bank-spread ds_reads; staging copies stored
// bytes verbatim via linear global_load_lds -> rule #21 satisfied).
__global__ __launch_bounds__(256)
void feat_kernel(const float* __restrict__ imgx,
                 const float* __restrict__ imgy,
                 const float* __restrict__ w,   // [4][1][2][2] flat
                 const float* __restrict__ b,   // [4]
                 unsigned char* __restrict__ fx,
                 unsigned char* __restrict__ fy,
                 float* __restrict__ norms)     // [2*NIMG]: x2 then y2
{
    __shared__ float simg[784];
    __shared__ float partial[4];
    const int gb = blockIdx.x;
    const bool isx = gb < NIMG;
    const int n = isx ? gb : gb - NIMG;
    const int t = threadIdx.x;
    const float* img = isx ? imgx : imgy;
    unsigned char* feat = isx ? fx : fy;

    const float4* ip4 = (const float4*)(img + (size_t)n * 784);
    if (t < 196) ((float4*)simg)[t] = ip4[t];
    __syncthreads();

    float ss = 0.f;
    unsigned pack = 0u;
    if (t < NPOS) {
        const int p = t / 14, q = t % 14;
        const float* px = &simg[p * 56 + q * 2];
        const float a0 = px[0], a1 = px[1], a2 = px[28], a3 = px[29];
        float f[4];
#pragma unroll
        for (int c = 0; c < 4; ++c) {
            f[c] = w[c * 4 + 0] * a0 + w[c * 4 + 1] * a1
                 + w[c * 4 + 2] * a2 + w[c * 4 + 3] * a3 + b[c];
            ss += f[c] * f[c];
        }
        pack = __builtin_amdgcn_cvt_pk_fp8_f32(f[0], f[1], 0, false);
        pack = __builtin_amdgcn_cvt_pk_fp8_f32(f[2], f[3], pack, true);
    }
    if (t < KPAD / 4) {
        // position of logical bytes k = 4t..4t+3 in stored layout
        const int p  = t * 4;
        const int s3 = (p >> 4) & 7;        // 16-B slot within 128-B slice
        const int pf = (p & ~127) | (((s3 ^ (n & 7)) << 4) | (p & 15));
        *(unsigned*)(feat + (size_t)n * KPAD + pf) = pack;  // zeros if t>=196
    }

#pragma unroll
    for (int off = 32; off > 0; off >>= 1) ss += __shfl_down(ss, off, 64);
    if ((t & 63) == 0) partial[t >> 6] = ss;
    __syncthreads();
    if (t == 0) norms[gb] = partial[0] + partial[1] + partial[2] + partial[3];
}

// ---------------- Gram kernel: 256x256, MX-scaled fp8 32x32x64, BK=128 -----
// NT GEMM C = A·B^T with exp(-max(x2+y2-2C,0)) epilogue.
// 8 waves (2M x 4N), double-buffered LDS (128 KB), 2 phases per K-tile,
// counted vmcnt(2) per K-tile (schedule identical to verified r5).
// MFMA: mfma_scale_f32_32x32x64_f8f6f4, fmt=fp8/fp8, unit E8M0 scales (0x7F)
// -> numerics identical to non-scaled fp8, 2x rate (m59: 4686 TF).

#define STAGE(GS, LD) do { \
    gload_lds16((GS), (LD)); \
    gload_lds16((GS) + 64 * KPAD, (LD) + 8192); } while (0)

// lane reads 32 contiguous stored K-bytes = two XOR-swizzled 16-B slots
#define RD_A(BUF, MH) do { \
    _Pragma("unroll") for (int mm = 0; mm < 2; ++mm) \
    _Pragma("unroll") for (int ks = 0; ks < 2; ++ks) { \
        const unsigned char* base = &As[BUF][0] \
            + (((MH) * 128 + mm * 64 + wrow) << 7); \
        const i32x4 lo = *(const i32x4*)(base + pxc[ks][0]); \
        const i32x4 hi4 = *(const i32x4*)(base + pxc[ks][1]); \
        af[mm][ks] = __builtin_shufflevector(lo, hi4, 0,1,2,3,4,5,6,7); \
    } } while (0)

#define RD_B(BUF, NH, BV) do { \
    _Pragma("unroll") for (int ks = 0; ks < 2; ++ks) { \
        const unsigned char* base = &Bs[BUF][0] + (((NH) * 128 + wcol) << 7); \
        const i32x4 lo = *(const i32x4*)(base + pxc[ks][0]); \
        const i32x4 hi4 = *(const i32x4*)(base + pxc[ks][1]); \
        BV[ks] = __builtin_shufflevector(lo, hi4, 0,1,2,3,4,5,6,7); \
    } } while (0)

#define MFMA_MH(MH) do { \
    __builtin_amdgcn_s_setprio(1); \
    _Pragma("unroll") for (int ks = 0; ks < 2; ++ks) { \
        const i32x8 a0 = af[0][ks], a1 = af[1][ks]; \
        const i32x8 v0 = b0[ks],    v1 = b1[ks]; \
        acc[(MH)*2+0][0] = __builtin_amdgcn_mfma_scale_f32_32x32x64_f8f6f4( \
            a0, v0, acc[(MH)*2+0][0], 0, 0, 0, 0x7F, 0, 0x7F); \
        acc[(MH)*2+1][0] = __builtin_amdgcn_mfma_scale_f32_32x32x64_f8f6f4( \
            a1, v0, acc[(MH)*2+1][0], 0, 0, 0, 0x7F, 0, 0x7F); \
        acc[(MH)*2+0][1] = __builtin_amdgcn_mfma_scale_f32_32x32x64_f8f6f4( \
            a0, v1, acc[(MH)*2+0][1], 0, 0, 0, 0x7F, 0, 0x7F); \
        acc[(MH)*2+1][1] = __builtin_amdgcn_mfma_scale_f32_32x32x64_f8f6f4( \
            a1, v1, acc[(MH)*2+1][1], 0, 0, 0, 0x7F, 0, 0x7F); \
    } \
    __builtin_amdgcn_s_setprio(0); } while (0)

// epilogue for half MH: C/D layout col=lane&31, row=(reg&3)+8*(reg>>2)+4*hi
// (shape-determined, dtype-independent: m121-m128)
#define EPI(MH) do { \
    _Pragma("unroll") for (int nh = 0; nh < 2; ++nh) { \
        const int colg = bCol + nh * 128 + wcol; \
        const float yv = y2[colg]; \
        _Pragma("unroll") for (int mm = 0; mm < 2; ++mm) { \
            const int rbase = bRow + (MH) * 128 + mm * 64 + wr * 32 + 4 * hi; \
            _Pragma("unroll") for (int gq = 0; gq < 4; ++gq) { \
                const f32x4 xv = *(const f32x4*)&x2[rbase + 8 * gq]; \
                _Pragma("unroll") for (int j = 0; j < 4; ++j) { \
                    float sq = fmaxf(xv[j] + yv \
                        - 2.0f * acc[(MH)*2+mm][nh][gq * 4 + j], 0.0f); \
                    out[(size_t)(rbase + 8 * gq + j) * NIMG + colg] = \
                        __expf(-sq); \
                } } } } } while (0)

#define BAR() __builtin_amdgcn_s_barrier()
#define LGKM0() do { asm volatile("s_waitcnt lgkmcnt(0)" ::: "memory"); \
                     __builtin_amdgcn_sched_barrier(0); } while (0)
#define VMW(N) asm volatile("s_waitcnt vmcnt(" #N ")" ::: "memory")

__global__ __launch_bounds__(512, 2)
void gram_kernel(const unsigned char* __restrict__ A,  // fx fp8 [NIMG][KPAD]
                 const unsigned char* __restrict__ B,  // fy fp8 [NIMG][KPAD]
                 const float* __restrict__ x2,         // [NIMG]
                 const float* __restrict__ y2,         // [NIMG]
                 float* __restrict__ out)              // [NIMG][NIMG]
{
    __shared__ __align__(16) unsigned char As[2][BM * 128];  // 64 KB
    __shared__ __align__(16) unsigned char Bs[2][BN * 128];  // 64 KB

    const int t    = threadIdx.x;
    const int lane = t & 63;
    const int w    = t >> 6;          // wave 0..7
    const int wr   = w >> 2;          // wave row 0..1
    const int wc   = w & 3;           // wave col 0..3

    // XCD-aware 2D-chunk swizzle: 256 blocks, 8 XCDs, bijective
    const int xb = blockIdx.x & 7, cb = blockIdx.x >> 3;  // cb in [0,32)
    const int bm = ((xb >> 1) << 2) | (cb & 3);           // [0,16)
    const int bn = ((xb & 1) << 3) | (cb >> 2);           // [0,16)
    const int bRow = bm * BM;
    const int bCol = bn * BN;

    f32x16 acc[4][2] = {};       // [mh*2+mm][nh], 128 regs
    i32x8 af[2][2];              // A frags: [mm][kstep]
    i32x8 b0[2], b1[2];          // B frags for NH=0 / NH=1, per kstep

    // fragment-read constants (32x32 f8f6f4: row/col = lane&31,
    // lane covers 32 contiguous k-bytes at k = (lane>>5)*32 + ks*64)
    const int r32  = lane & 31;
    const int hi   = lane >> 5;
    const int f7   = r32 & 7;
    const int wrow = wr * 32 + r32;   // A row within half
    const int wcol = wc * 32 + r32;   // B col within half
    int pxc[2][2];
#pragma unroll
    for (int ks = 0; ks < 2; ++ks)
#pragma unroll
        for (int bb = 0; bb < 2; ++bb)
            pxc[ks][bb] = (((ks * 4) | (hi * 2) | bb) ^ f7) << 4;

    // staging: wave w covers rows w*8 + (lane>>3) of each 64-row group,
    // 16-B col chunk lane&7; stored layout is pre-swizzled -> linear copy.
    const int lr = lane >> 3;
    const unsigned char* Asrc = A + (size_t)(bRow + w * 8 + lr) * KPAD
                                  + (lane & 7) * 16;
    const unsigned char* Bsrc = B + (size_t)(bCol + w * 8 + lr) * KPAD
                                  + (lane & 7) * 16;

    // LDS dests (wave-uniform): half h at h*16384, wave slot w*1024
    unsigned char* dA0h0 = &As[0][w << 10];
    unsigned char* dA0h1 = &As[0][16384 + (w << 10)];
    unsigned char* dA1h0 = &As[1][w << 10];
    unsigned char* dA1h1 = &As[1][16384 + (w << 10)];
    unsigned char* dB0h0 = &Bs[0][w << 10];
    unsigned char* dB0h1 = &Bs[0][16384 + (w << 10)];
    unsigned char* dB1h0 = &Bs[1][w << 10];
    unsigned char* dB1h1 = &Bs[1][16384 + (w << 10)];

    // prologue: tile0 full into buf0 + tile1.Ah0 into buf1
    STAGE(Asrc,              dA0h0);
    STAGE(Bsrc,              dB0h0);
    STAGE(Asrc + 128 * KPAD, dA0h1);
    STAGE(Bsrc + 128 * KPAD, dB0h1);
    STAGE(Asrc + 128,        dA1h0);
    VMW(2);
    BAR();

    // main loop: tiles 0..5 (tile t in buf t&1)
    for (int kt = 0; kt < 6; ++kt) {
        const int c   = kt & 1;
        const int o1  = (kt + 1) * 128;   // next tile k-byte offset
        const int o2  = (kt + 2) * 128;
        unsigned char* nAh1 = c ? dA0h1 : dA1h1;
        unsigned char* nBh0 = c ? dB0h0 : dB1h0;
        unsigned char* nBh1 = c ? dB0h1 : dB1h1;
        unsigned char* cAh0 = c ? dA1h0 : dA0h0;
        // Q1: read Ah0 + both B halves; stage next-tile Ah1, Bh0
        RD_A(c, 0); RD_B(c, 0, b0); RD_B(c, 1, b1);
        STAGE(Asrc + 128 * KPAD + o1, nAh1);
        STAGE(Bsrc + o1,              nBh0);
        BAR(); LGKM0(); MFMA_MH(0); BAR();
        // Q2: read Ah1; stage next-tile Bh1 + tile(t+2).Ah0 into cur buf
        RD_A(c, 1);
        STAGE(Bsrc + 128 * KPAD + o1, nBh1);
        if (kt < 5) STAGE(Asrc + o2, cAh0);
        BAR(); LGKM0(); MFMA_MH(1);
        if (kt < 5) { VMW(2); } else { VMW(0); }
        BAR();
    }

    // tail: tile 6 in buf0, fully staged + drained; epilogue interleaved
    RD_A(0, 0); RD_B(0, 0, b0); RD_B(0, 1, b1);
    LGKM0(); MFMA_MH(0); EPI(0);
    RD_A(0, 1);
    LGKM0(); MFMA_MH(1); EPI(1);
}

extern "C" void kernel_launch(void* const* d_in, const int* in_sizes, int n_in,
                              void* d_out, int out_size, void* d_ws, size_t ws_size,
                              hipStream_t stream) {
    const float* x  = (const float*)d_in[0];
    const float* y  = (const float*)d_in[1];
    const float* cw = (const float*)d_in[2];
    const float* cb = (const float*)d_in[3];
    float* out = (float*)d_out;

    char* ws = (char*)d_ws;
    const size_t featBytes = (size_t)NIMG * KPAD;  // 3.67 MB
    unsigned char* fx = (unsigned char*)ws;
    unsigned char* fy = (unsigned char*)(ws + featBytes);
    float* x2 = (float*)(ws + 2 * featBytes);
    float* y2 = x2 + NIMG;

    feat_kernel<<<2 * NIMG, 256, 0, stream>>>(x, y, cw, cb, fx, fy, x2);

    gram_kernel<<<256, 512, 0, stream>>>(fx, fy, x2, y2, out);
}